// Round 25
// baseline (227.209 us; speedup 1.0000x reference)
//
#include <hip/hip_runtime.h>
#include <hip/hip_bf16.h>

#define T_ 2048
#define SCALE_ 0.07216878364870322f  // 192^-0.5

typedef __bf16 bf16x8 __attribute__((ext_vector_type(8)));
typedef float f32x4 __attribute__((ext_vector_type(4)));
typedef float f32x16 __attribute__((ext_vector_type(16)));

__device__ inline bf16x8 load8f(const float* p) {
    const float4* f = reinterpret_cast<const float4*>(p);
    float4 a = f[0], b = f[1];
    bf16x8 r;
    r[0] = (__bf16)a.x; r[1] = (__bf16)a.y; r[2] = (__bf16)a.z; r[3] = (__bf16)a.w;
    r[4] = (__bf16)b.x; r[5] = (__bf16)b.y; r[6] = (__bf16)b.z; r[7] = (__bf16)b.w;
    return r;
}

__device__ inline void gld_lds16(const void* g, void* l) {
    __builtin_amdgcn_global_load_lds((const __attribute__((address_space(1))) void*)g,
                                     (__attribute__((address_space(3))) void*)l, 16, 0, 0);
}

// ---------------- transpose-convert tile body ---------------------------------
__device__ __forceinline__ void tc_body(
    const float* __restrict__ W, __bf16* __restrict__ Wt, int K, int N,
    int k0, int n0, __bf16 (*tl)[72])
{
    const int tid = threadIdx.x;
    const bool in = n0 < N;
    #pragma unroll
    for (int it = 0; it < 2; ++it) {
        int chunk = tid + it * 256;
        int r = chunk >> 3;
        int c8 = (chunk & 7) * 8;
        float4 a = {0,0,0,0}, b = {0,0,0,0};
        if (in) {
            const float* p = W + (size_t)(k0 + r) * N + n0 + c8;
            a = *reinterpret_cast<const float4*>(p);
            b = *reinterpret_cast<const float4*>(p + 4);
        }
        tl[c8+0][r] = (__bf16)a.x; tl[c8+1][r] = (__bf16)a.y;
        tl[c8+2][r] = (__bf16)a.z; tl[c8+3][r] = (__bf16)a.w;
        tl[c8+4][r] = (__bf16)b.x; tl[c8+5][r] = (__bf16)b.y;
        tl[c8+6][r] = (__bf16)b.z; tl[c8+7][r] = (__bf16)b.w;
    }
    __syncthreads();
    #pragma unroll
    for (int it = 0; it < 2; ++it) {
        int chunk = tid + it * 256;
        int n = chunk >> 3;
        int k8 = (chunk & 7) * 8;
        bf16x8 v = *reinterpret_cast<const bf16x8*>(&tl[n][k8]);
        *reinterpret_cast<bf16x8*>(Wt + (size_t)(n0 + n) * K + k0 + k8) = v;
    }
}

// ---------------- prep1: cvt(hidden) + w_q_a^T + w_kv_a^T --------------------
__global__ __launch_bounds__(256) void prep1(
    const float* __restrict__ hidden, __bf16* __restrict__ hidden_bf,
    const float* __restrict__ w_q_a, const float* __restrict__ w_kv_a,
    __bf16* __restrict__ wbuf)
{
    __shared__ __bf16 tl[64][72];
    const int b = blockIdx.x;
    if (b < 2048) {
        int i = b * 256 + threadIdx.x;
        *reinterpret_cast<bf16x8*>(hidden_bf + (size_t)i * 8) = load8f(hidden + (size_t)i * 8);
    } else if (b < 2816) {
        int idx = b - 2048;
        tc_body(w_q_a, wbuf, 2048, 1536, (idx & 31) * 64, (idx >> 5) * 64, tl);
    } else {
        int idx = b - 2816;
        tc_body(w_kv_a, wbuf + (size_t)1536 * 2048, 2048, 576, (idx & 31) * 64, (idx >> 5) * 64, tl);
    }
}

// ---------------- prep2: w_q_b^T + w_kv_b^T ----------------------------------
__global__ __launch_bounds__(256) void prep2(
    const float* __restrict__ w_q_b, __bf16* __restrict__ wbuf,
    const float* __restrict__ w_kv_b, __bf16* __restrict__ wbuf2)
{
    __shared__ __bf16 tl[64][72];
    const int b = blockIdx.x;
    if (b < 1152) {
        tc_body(w_q_b, wbuf, 1536, 3072, (b % 24) * 64, (b / 24) * 64, tl);
    } else {
        int idx = b - 1152;
        tc_body(w_kv_b, wbuf2, 512, 4096, (idx & 7) * 64, (idx >> 3) * 64, tl);
    }
}

// ---------------- GEMM body: C[128,128] tile at (m0,n0) ----------------------
template <typename TC>
__device__ __forceinline__ void gemm_body(
    const __bf16* __restrict__ A, const __bf16* __restrict__ Bt,
    TC* __restrict__ C, int K, int Nstore, int ldc, int m0, int n0,
    __bf16* As, __bf16* Bs)
{
    const int tid = threadIdx.x, lane = tid & 63, wid = tid >> 6;
    const int l15 = lane & 15, lg = lane >> 4;
    const int wr = (wid >> 1) * 64, wc = (wid & 1) * 64;

    const int srow = wid * 32 + (lane >> 3);
    const int scol = ((lane & 7) ^ (lane >> 3)) * 8;
    const __bf16* Ag = A  + (size_t)(m0 + srow) * K + scol;
    const __bf16* Bg = Bt + (size_t)(n0 + srow) * K + scol;
    const int lbase = wid * 4096;

    f32x4 acc[4][4] = {};

    {
        char* la = (char*)As + lbase;
        char* lb = (char*)Bs + lbase;
        #pragma unroll
        for (int i = 0; i < 4; ++i) {
            gld_lds16(Ag + (size_t)i * 8 * K, la + i * 1024);
            gld_lds16(Bg + (size_t)i * 8 * K, lb + i * 1024);
        }
    }
    __syncthreads();

    int cur = 0;
    for (int k0 = 0; k0 < K; k0 += 64) {
        if (k0 + 64 < K) {
            char* la = (char*)As + (cur ^ 1) * 16384 + lbase;
            char* lb = (char*)Bs + (cur ^ 1) * 16384 + lbase;
            #pragma unroll
            for (int i = 0; i < 4; ++i) {
                gld_lds16(Ag + (size_t)i * 8 * K + k0 + 64, la + i * 1024);
                gld_lds16(Bg + (size_t)i * 8 * K + k0 + 64, lb + i * 1024);
            }
        }

        bf16x8 af[4][2], bf[4][2];
        #pragma unroll
        for (int i = 0; i < 4; ++i) {
            const int Ra = wr + i * 16 + l15;
            const int Rb = wc + i * 16 + l15;
            const int ca = (lg ^ (Ra & 7)) * 16;
            const int cb = (lg ^ (Rb & 7)) * 16;
            const char* pa = (const char*)As + cur * 16384 + Ra * 128;
            const char* pb = (const char*)Bs + cur * 16384 + Rb * 128;
            af[i][0] = *reinterpret_cast<const bf16x8*>(pa + ca);
            af[i][1] = *reinterpret_cast<const bf16x8*>(pa + (ca ^ 64));
            bf[i][0] = *reinterpret_cast<const bf16x8*>(pb + cb);
            bf[i][1] = *reinterpret_cast<const bf16x8*>(pb + (cb ^ 64));
        }
        #pragma unroll
        for (int h = 0; h < 2; ++h)
            #pragma unroll
            for (int i = 0; i < 4; ++i)
                #pragma unroll
                for (int j = 0; j < 4; ++j)
                    acc[i][j] = __builtin_amdgcn_mfma_f32_16x16x32_bf16(af[i][h], bf[j][h], acc[i][j], 0, 0, 0);

        __syncthreads();
        cur ^= 1;
    }

    #pragma unroll
    for (int i = 0; i < 4; ++i)
        #pragma unroll
        for (int j = 0; j < 4; ++j)
            #pragma unroll
            for (int e = 0; e < 4; ++e) {
                int r = m0 + wr + i * 16 + lg * 4 + e;
                int c = n0 + wc + j * 16 + l15;
                if (c < Nstore)
                    C[(size_t)r * ldc + c] = (TC)acc[i][j][e];
            }
}

template <typename TC>
__global__ __launch_bounds__(256) void gemm_bt(
    const __bf16* __restrict__ A, const __bf16* __restrict__ Bt,
    TC* __restrict__ C, int M, int N, int K, int Nstore, int ldc)
{
    __shared__ __bf16 As[2 * 128 * 64];
    __shared__ __bf16 Bs[2 * 128 * 64];
    gemm_body<TC>(A, Bt, C, K, Nstore, ldc, blockIdx.x * 128, blockIdx.y * 128, As, Bs);
}

__global__ __launch_bounds__(256) void gemm_bt_pair(
    const __bf16* __restrict__ A0, const __bf16* __restrict__ B0, __bf16* __restrict__ C0,
    int N0, int K0, int nby0,
    const __bf16* __restrict__ A1, const __bf16* __restrict__ B1, __bf16* __restrict__ C1,
    int N1, int K1)
{
    __shared__ __bf16 As[2 * 128 * 64];
    __shared__ __bf16 Bs[2 * 128 * 64];
    if ((int)blockIdx.y < nby0)
        gemm_body<__bf16>(A0, B0, C0, K0, N0, N0, blockIdx.x * 128, blockIdx.y * 128, As, Bs);
    else
        gemm_body<__bf16>(A1, B1, C1, K1, N1, N1, blockIdx.x * 128, (blockIdx.y - nby0) * 128, As, Bs);
}

// ---------------- Fused RMSNorm: q (1536) + kv (512) per row ------------------
__global__ __launch_bounds__(256) void rmsnorm_fused(
    const __bf16* __restrict__ qkv_a,
    const float* __restrict__ qw, const float* __restrict__ kw,
    __bf16* __restrict__ q_a_n, __bf16* __restrict__ kv_a_n)
{
    const int t = blockIdx.x, tid = threadIdx.x, wid = tid >> 6;
    const bool isq = tid < 192;
    const __bf16* src = qkv_a + (size_t)t * 2176 + (isq ? tid * 8 : 1536 + (tid - 192) * 8);
    float x[8];
    float ss = 0.f;
    bf16x8 v = *reinterpret_cast<const bf16x8*>(src);
    #pragma unroll
    for (int e = 0; e < 8; ++e) { x[e] = (float)v[e]; ss += x[e] * x[e]; }
    #pragma unroll
    for (int m = 1; m < 64; m <<= 1) ss += __shfl_xor(ss, m, 64);
    __shared__ float red[4];
    if ((tid & 63) == 0) red[wid] = ss;
    __syncthreads();
    float scale;
    const float* w;
    if (isq) {
        scale = rsqrtf((red[0] + red[1] + red[2]) / 1536.f + 1e-6f);
        w = qw + tid * 8;
    } else {
        scale = rsqrtf(red[3] / 512.f + 1e-6f);
        w = kw + (tid - 192) * 8;
    }
    float4 w0 = *reinterpret_cast<const float4*>(w);
    float4 w1 = *reinterpret_cast<const float4*>(w + 4);
    bf16x8 o;
    o[0] = (__bf16)(x[0] * scale * w0.x); o[1] = (__bf16)(x[1] * scale * w0.y);
    o[2] = (__bf16)(x[2] * scale * w0.z); o[3] = (__bf16)(x[3] * scale * w0.w);
    o[4] = (__bf16)(x[4] * scale * w1.x); o[5] = (__bf16)(x[5] * scale * w1.y);
    o[6] = (__bf16)(x[6] * scale * w1.z); o[7] = (__bf16)(x[7] * scale * w1.w);
    if (isq)
        *reinterpret_cast<bf16x8*>(q_a_n + (size_t)t * 1536 + tid * 8) = o;
    else
        *reinterpret_cast<bf16x8*>(kv_a_n + (size_t)t * 512 + (tid - 192) * 8) = o;
}

// ---------------- Fused RoPE(q)+Kprep  |  V-transpose (one launch) ------------
// kh stored PLAIN row-major now (swizzle moved into attn's gld_lds source).
__global__ __launch_bounds__(256) void rope_vtrans(
    const int* __restrict__ positions, __bf16* __restrict__ q,
    const __bf16* __restrict__ kv, const __bf16* __restrict__ qkv_a,
    __bf16* __restrict__ kh, __bf16* __restrict__ vt)
{
    const int b = blockIdx.x, tid = threadIdx.x;
    if (b < 2048) {
        const int t = b;
        __shared__ float cs[32], sn[32];
        __shared__ __bf16 kpe[64];
        if (tid < 32) {
            float pos = (float)positions[t];
            float invf = powf(10000.f, -(float)tid / 32.f);
            float c = cosf(pos * invf), s = sinf(pos * invf);
            cs[tid] = c; sn[tid] = s;
            float x1 = (float)qkv_a[(size_t)t * 2176 + 2048 + 2 * tid];
            float x2 = (float)qkv_a[(size_t)t * 2176 + 2049 + 2 * tid];
            kpe[2 * tid]     = (__bf16)(x1 * c - x2 * s);
            kpe[2 * tid + 1] = (__bf16)(x2 * c + x1 * s);
        }
        __syncthreads();
        #pragma unroll
        for (int it = 0; it < 2; ++it) {
            int p = tid + it * 256;
            int h = p >> 5, i = p & 31;
            size_t base = (size_t)t * 3072 + h * 192 + 128 + 2 * i;
            float x1 = (float)q[base], x2 = (float)q[base + 1];
            q[base]     = (__bf16)(x1 * cs[i] - x2 * sn[i]);
            q[base + 1] = (__bf16)(x2 * cs[i] + x1 * sn[i]);
        }
        const int h = tid >> 4, c = tid & 15;
        bf16x8 v = *reinterpret_cast<const bf16x8*>(kv + (size_t)t * 4096 + h * 256 + c * 8);
        *reinterpret_cast<bf16x8*>(kh + ((size_t)h * T_ + t) * 192 + c * 8) = v;
        if (c < 8) {
            bf16x8 p = *reinterpret_cast<const bf16x8*>(&kpe[c * 8]);
            *reinterpret_cast<bf16x8*>(kh + ((size_t)h * T_ + t) * 192 + 128 + c * 8) = p;
        }
    } else {
        __shared__ __bf16 tile[128][72];
        const int idx = b - 2048;
        const int t0 = (idx & 31) * 64;
        const int h  = idx >> 5;
        #pragma unroll
        for (int it = 0; it < 4; ++it) {
            int chunk = tid + it * 256;
            int r = chunk >> 4;
            int d8 = (chunk & 15) * 8;
            bf16x8 v = *reinterpret_cast<const bf16x8*>(kv + (size_t)(t0 + r) * 4096 + h * 256 + 128 + d8);
            #pragma unroll
            for (int e = 0; e < 8; ++e) tile[d8 + e][r] = v[e];
        }
        __syncthreads();
        #pragma unroll
        for (int it = 0; it < 4; ++it) {
            int chunk = tid + it * 256;
            int d = chunk >> 3;
            int t8 = (chunk & 7) * 8;
            bf16x8 v = *reinterpret_cast<const bf16x8*>(&tile[d][t8]);
            *reinterpret_cast<bf16x8*>(vt + ((size_t)h * 128 + d) * 2048 + t0 + t8) = v;
        }
    }
}

// ---------------- Flash attention (+ fused w_o transpose tail) ----------------
// 32KB LDS (nope-128 dims staged per wave, 8KB; rope-64 dims read from global
// per tile) -> 4 blocks/CU instead of 2. Swizzle lives in the gld_lds SOURCE
// address (per-lane global, rule 21); LDS reads XOR the same pattern.
__device__ inline unsigned pk2(float a, float b) {
    union { __bf16 h[2]; unsigned u; } z;
    z.h[0] = (__bf16)a; z.h[1] = (__bf16)b;
    return z.u;
}

union AttnSmem {
    char kstage[4][8192];            // 4 waves x 8KB K-nope tile (32,768 B)
    struct {
        float mls[2][4][32];
        float linv[32];
        float obuf[32][129];
    } c;
    __bf16 tl[64][72];               // w_o transpose tile
};

__global__ __launch_bounds__(256, 2) void attn_wo(
    const __bf16* __restrict__ q, const __bf16* __restrict__ kh,
    const __bf16* __restrict__ vt, __bf16* __restrict__ attn,
    const float* __restrict__ w_o, __bf16* __restrict__ wot)
{
    __shared__ AttnSmem sm;
    const int b = blockIdx.x;
    if (b >= 1024) {   // w_o transpose tile: 2048x2048, 32x32 tiles
        const int idx = b - 1024;
        tc_body(w_o, wot, 2048, 2048, (idx & 31) * 64, (idx >> 5) * 64, sm.tl);
        return;
    }

    const int tid = threadIdx.x;
    const int lane = tid & 63, wid = tid >> 6;      // 0..3
    const int q31 = lane & 31, hi = lane >> 5;
    const int h = b & 15;
    const int qt = 63 - (b >> 4);                    // heavy-first
    const int q0 = qt * 32;
    const int ntile = qt + 1;

    const __bf16* Khh = kh + (size_t)h * T_ * 192;
    const __bf16* Vt  = vt + (size_t)h * 128 * T_;
    const __bf16* Qp  = q + (size_t)(q0 + q31) * 3072 + h * 192;

    bf16x8 aq[12];
    #pragma unroll
    for (int c = 0; c < 12; ++c)
        aq[c] = *reinterpret_cast<const bf16x8*>(Qp + c * 16 + hi * 8);

    f32x16 o[4] = {};
    float m_i = -1e30f, l_i = 0.f;

    char* kbuf = sm.kstage[wid];
    // staging source: lane covers row = i*4 + (lane>>4), chunk = lane&15 of
    // the 32x(128dim) nope tile; swizzled source chunk = chunk ^ (row&7).
    const int srow = lane >> 4;             // 0..3 within 4-row group
    const int schunk = lane & 15;

    // prologue: stage tile `wid`
    if (wid < ntile) {
        #pragma unroll
        for (int i = 0; i < 8; ++i) {
            const int r = i * 4 + srow;
            gld_lds16(Khh + (size_t)(wid * 32 + r) * 192 + ((schunk ^ (r & 7)) * 8),
                      kbuf + i * 1024 + (lane & 15) * 16 + srow * 256);
        }
    }

    for (int it = wid; it < ntile; it += 4) {
        // staging of this tile complete
        asm volatile("s_waitcnt vmcnt(0)" ::: "memory");
        __builtin_amdgcn_sched_barrier(0);

        // K nope fragments from LDS (swizzled chunks)
        bf16x8 kc[12];
        #pragma unroll
        for (int c = 0; c < 8; ++c) {
            const int p = (2 * c + hi) ^ (q31 & 7);
            kc[c] = *reinterpret_cast<const bf16x8*>(kbuf + q31 * 256 + p * 16);
        }
        asm volatile("s_waitcnt lgkmcnt(0)" ::: "memory");
        __builtin_amdgcn_sched_barrier(0);

        const int s0 = it * 32;
        // K rope fragments direct from global (plain layout)
        #pragma unroll
        for (int c = 8; c < 12; ++c)
            kc[c] = *reinterpret_cast<const bf16x8*>(
                Khh + (size_t)(s0 + q31) * 192 + 128 + (c - 8) * 16 + hi * 8);

        // V fragments (PV's wait leaves the later-issued stage in flight)
        bf16x8 vf[4][2];
        #pragma unroll
        for (int n = 0; n < 4; ++n)
            #pragma unroll
            for (int m = 0; m < 2; ++m)
                vf[n][m] = *reinterpret_cast<const bf16x8*>(
                    Vt + (size_t)(n * 32 + q31) * 2048 + s0 + (2 * m + hi) * 8);

        // issue next stage (async, un-sinkable; in flight through next loop top)
        const bool notlast = (it + 4 < ntile);
        if (notlast) {
            #pragma unroll
            for (int i = 0; i < 8; ++i) {
                const int r = i * 4 + srow;
                gld_lds16(Khh + (size_t)((it + 4) * 32 + r) * 192 + ((schunk ^ (r & 7)) * 8),
                          kbuf + i * 1024 + (lane & 15) * 16 + srow * 256);
            }
        }

        // QK^T (swapped): S^T[kpos][q]
        f32x16 sA = {}, sB = {};
        __builtin_amdgcn_s_setprio(1);
        #pragma unroll
        for (int c = 0; c < 12; c += 2) {
            sA = __builtin_amdgcn_mfma_f32_32x32x16_bf16(kc[c],     aq[c],     sA, 0, 0, 0);
            sB = __builtin_amdgcn_mfma_f32_32x32x16_bf16(kc[c + 1], aq[c + 1], sB, 0, 0, 0);
        }
        __builtin_amdgcn_s_setprio(0);

        float v[16];
        #pragma unroll
        for (int r = 0; r < 16; ++r) v[r] = (sA[r] + sB[r]) * SCALE_;
        if (it == qt) {   // diagonal tile: mask k > q
            #pragma unroll
            for (int r = 0; r < 16; ++r) {
                int crow = (r & 3) + 8 * (r >> 2) + 4 * hi;
                if (crow > q31) v[r] = -1e30f;
            }
        }
        float mx = v[0];
        #pragma unroll
        for (int r = 1; r < 16; ++r) mx = fmaxf(mx, v[r]);
        mx = fmaxf(mx, __shfl_xor(mx, 32, 64));
        const bool skip = __all(mx <= m_i);
        float mnew = fmaxf(m_i, mx);
        float fsc = skip ? 1.f : __expf(m_i - mnew);
        m_i = mnew;
        float ps = 0.f;
        #pragma unroll
        for (int r = 0; r < 16; ++r) { v[r] = __expf(v[r] - mnew); ps += v[r]; }
        ps += __shfl_xor(ps, 32, 64);
        l_i = l_i * fsc + ps;
        if (!skip) {
            #pragma unroll
            for (int n = 0; n < 4; ++n) o[n] *= fsc;
        }

        // pack P to bf16; exchange halves across lane^32
        unsigned w[8], xw[8];
        #pragma unroll
        for (int i = 0; i < 8; ++i) w[i] = pk2(v[2 * i], v[2 * i + 1]);
        #pragma unroll
        for (int i = 0; i < 8; ++i) xw[i] = __shfl_xor(w[i], 32, 64);
        union { unsigned u[4]; bf16x8 v; } P0, P1;
        P0.u[0] = hi ? xw[2] : w[0]; P0.u[1] = hi ? xw[3] : w[1];
        P0.u[2] = hi ? w[2] : xw[0]; P0.u[3] = hi ? w[3] : xw[1];
        P1.u[0] = hi ? xw[6] : w[4]; P1.u[1] = hi ? xw[7] : w[5];
        P1.u[2] = hi ? w[6] : xw[4]; P1.u[3] = hi ? w[7] : xw[5];

        __builtin_amdgcn_s_setprio(1);
        #pragma unroll
        for (int n = 0; n < 4; ++n) {
            o[n] = __builtin_amdgcn_mfma_f32_32x32x16_bf16(vf[n][0], P0.v, o[n], 0, 0, 0);
            o[n] = __builtin_amdgcn_mfma_f32_32x32x16_bf16(vf[n][1], P1.v, o[n], 0, 0, 0);
        }
        __builtin_amdgcn_s_setprio(0);
    }

    // all my gld_lds consumed (loop-top vmcnt); barrier, then union -> combine
    __syncthreads();
    if (hi == 0) { sm.c.mls[0][wid][q31] = m_i; sm.c.mls[1][wid][q31] = l_i; }
    __syncthreads();
    float M = fmaxf(fmaxf(sm.c.mls[0][0][q31], sm.c.mls[0][1][q31]),
                    fmaxf(sm.c.mls[0][2][q31], sm.c.mls[0][3][q31]));
    float L = sm.c.mls[1][0][q31] * __expf(sm.c.mls[0][0][q31] - M)
            + sm.c.mls[1][1][q31] * __expf(sm.c.mls[0][1][q31] - M)
            + sm.c.mls[1][2][q31] * __expf(sm.c.mls[0][2][q31] - M)
            + sm.c.mls[1][3][q31] * __expf(sm.c.mls[0][3][q31] - M);
    float F = __expf(m_i - M);
    if (wid == 0 && hi == 0) sm.c.linv[q31] = 1.f / L;

    #pragma unroll
    for (int rd = 0; rd < 4; ++rd) {
        if (wid == rd) {
            if (rd == 0) {
                #pragma unroll
                for (int n = 0; n < 4; ++n)
                    #pragma unroll
                    for (int r = 0; r < 16; ++r) {
                        int d = (r & 3) + 8 * (r >> 2) + 4 * hi + 32 * n;
                        sm.c.obuf[q31][d] = F * o[n][r];
                    }
            } else {
                #pragma unroll
                for (int n = 0; n < 4; ++n)
                    #pragma unroll
                    for (int r = 0; r < 16; ++r) {
                        int d = (r & 3) + 8 * (r >> 2) + 4 * hi + 32 * n;
                        sm.c.obuf[q31][d] += F * o[n][r];
                    }
            }
        }
        __syncthreads();
    }

    // store: 256 threads x 2 iters = 32 rows x 16 chunks
    #pragma unroll
    for (int it2 = 0; it2 < 2; ++it2) {
        int cidx = tid + it2 * 256;
        int row = cidx >> 4, c8 = (cidx & 15) * 8;
        float inv = sm.c.linv[row];
        bf16x8 vv;
        #pragma unroll
        for (int j = 0; j < 8; ++j)
            vv[j] = (__bf16)(sm.c.obuf[row][c8 + j] * inv);
        *reinterpret_cast<bf16x8*>(attn + (size_t)(q0 + row) * 2048 + h * 128 + c8) = vv;
    }
}

// -----------------------------------------------------------------------------
extern "C" void kernel_launch(void* const* d_in, const int* in_sizes, int n_in,
                              void* d_out, int out_size, void* d_ws, size_t ws_size,
                              hipStream_t stream)
{
    const int*   positions = (const int*)d_in[0];
    const float* hidden    = (const float*)d_in[1];
    const float* w_q_a     = (const float*)d_in[2];
    const float* q_a_ln_w  = (const float*)d_in[3];
    const float* w_q_b     = (const float*)d_in[4];
    const float* w_kv_a    = (const float*)d_in[5];
    const float* kv_a_ln_w = (const float*)d_in[6];
    const float* w_kv_b    = (const float*)d_in[7];
    const float* w_o       = (const float*)d_in[8];

    char* ws = (char*)d_ws;
    __bf16* hidden_bf = (__bf16*)(ws);                 // 2048x2048      8,388,608
    __bf16* vt        = (__bf16*)(ws);                 // 16x128x2048 (overlays hidden_bf)
    __bf16* wbuf      = (__bf16*)(ws + 8388608);       // W^T scratch    9,437,184
    __bf16* qkv_a     = (__bf16*)(ws + 17825792);      // 2048x2176      8,912,896
    __bf16* attn      = (__bf16*)(ws + 17825792);      // 2048x2048 (overlays qkv_a)
    __bf16* q_a_n     = (__bf16*)(ws + 26738688);      // 2048x1536      6,291,456
    __bf16* q         = (__bf16*)(ws + 33030144);      // 2048x3072     12,582,912
    __bf16* kv_a_n    = (__bf16*)(ws + 45613056);      // 2048x512       2,097,152
    __bf16* kv        = (__bf16*)(ws + 47710208);      // 2048x4096     16,777,216
    __bf16* wot       = (__bf16*)(ws + 47710208);      // 2048x2048 w_o^T (overlays kv after use)
    __bf16* kh        = (__bf16*)(ws + 64487424);      // 16x2048x192   12,582,912
    __bf16* wbuf2     = (__bf16*)(ws + 77070336);      // 512x4096 W^T   4,194,304

    dim3 blk(256);
    prep1<<<dim3(3136), blk, 0, stream>>>(hidden, hidden_bf, w_q_a, w_kv_a, wbuf);
    gemm_bt<__bf16><<<dim3(16, 17), blk, 0, stream>>>(hidden_bf, wbuf, qkv_a, 2048, 2176, 2048, 2112, 2176);
    rmsnorm_fused<<<dim3(2048), blk, 0, stream>>>(qkv_a, q_a_ln_w, kv_a_ln_w, q_a_n, kv_a_n);

    prep2<<<dim3(1664), blk, 0, stream>>>(w_q_b, wbuf, w_kv_b, wbuf2);
    gemm_bt_pair<<<dim3(16, 56), blk, 0, stream>>>(
        q_a_n, wbuf, q, 3072, 1536, 24,
        kv_a_n, wbuf2, kv, 4096, 512);

    rope_vtrans<<<dim3(2560), blk, 0, stream>>>(positions, q, kv, qkv_a, kh, vt);
    attn_wo<<<dim3(2048), blk, 0, stream>>>(q, kh, vt, attn, w_o, wot);

    gemm_bt<float><<<dim3(16, 16), blk, 0, stream>>>(attn, wot, (float*)d_out, 2048, 2048, 2048, 2048, 2048);
}

// Round 26
// 215.136 us; speedup vs baseline: 1.0561x; 1.0561x over previous
//
#include <hip/hip_runtime.h>
#include <hip/hip_bf16.h>

#define T_ 2048
#define SCALE_ 0.07216878364870322f  // 192^-0.5

typedef __bf16 bf16x8 __attribute__((ext_vector_type(8)));
typedef float f32x4 __attribute__((ext_vector_type(4)));
typedef float f32x16 __attribute__((ext_vector_type(16)));

__device__ inline bf16x8 load8f(const float* p) {
    const float4* f = reinterpret_cast<const float4*>(p);
    float4 a = f[0], b = f[1];
    bf16x8 r;
    r[0] = (__bf16)a.x; r[1] = (__bf16)a.y; r[2] = (__bf16)a.z; r[3] = (__bf16)a.w;
    r[4] = (__bf16)b.x; r[5] = (__bf16)b.y; r[6] = (__bf16)b.z; r[7] = (__bf16)b.w;
    return r;
}

__device__ inline void gld_lds16(const void* g, void* l) {
    __builtin_amdgcn_global_load_lds((const __attribute__((address_space(1))) void*)g,
                                     (__attribute__((address_space(3))) void*)l, 16, 0, 0);
}

// ---------------- transpose-convert tile body ---------------------------------
__device__ __forceinline__ void tc_body(
    const float* __restrict__ W, __bf16* __restrict__ Wt, int K, int N,
    int k0, int n0, __bf16 (*tl)[72])
{
    const int tid = threadIdx.x;
    const bool in = n0 < N;
    #pragma unroll
    for (int it = 0; it < 2; ++it) {
        int chunk = tid + it * 256;
        int r = chunk >> 3;
        int c8 = (chunk & 7) * 8;
        float4 a = {0,0,0,0}, b = {0,0,0,0};
        if (in) {
            const float* p = W + (size_t)(k0 + r) * N + n0 + c8;
            a = *reinterpret_cast<const float4*>(p);
            b = *reinterpret_cast<const float4*>(p + 4);
        }
        tl[c8+0][r] = (__bf16)a.x; tl[c8+1][r] = (__bf16)a.y;
        tl[c8+2][r] = (__bf16)a.z; tl[c8+3][r] = (__bf16)a.w;
        tl[c8+4][r] = (__bf16)b.x; tl[c8+5][r] = (__bf16)b.y;
        tl[c8+6][r] = (__bf16)b.z; tl[c8+7][r] = (__bf16)b.w;
    }
    __syncthreads();
    #pragma unroll
    for (int it = 0; it < 2; ++it) {
        int chunk = tid + it * 256;
        int n = chunk >> 3;
        int k8 = (chunk & 7) * 8;
        bf16x8 v = *reinterpret_cast<const bf16x8*>(&tl[n][k8]);
        *reinterpret_cast<bf16x8*>(Wt + (size_t)(n0 + n) * K + k0 + k8) = v;
    }
}

// ---------------- prep1: cvt(hidden) + w_q_a^T + w_kv_a^T --------------------
__global__ __launch_bounds__(256) void prep1(
    const float* __restrict__ hidden, __bf16* __restrict__ hidden_bf,
    const float* __restrict__ w_q_a, const float* __restrict__ w_kv_a,
    __bf16* __restrict__ wbuf)
{
    __shared__ __bf16 tl[64][72];
    const int b = blockIdx.x;
    if (b < 2048) {
        int i = b * 256 + threadIdx.x;
        *reinterpret_cast<bf16x8*>(hidden_bf + (size_t)i * 8) = load8f(hidden + (size_t)i * 8);
    } else if (b < 2816) {
        int idx = b - 2048;
        tc_body(w_q_a, wbuf, 2048, 1536, (idx & 31) * 64, (idx >> 5) * 64, tl);
    } else {
        int idx = b - 2816;
        tc_body(w_kv_a, wbuf + (size_t)1536 * 2048, 2048, 576, (idx & 31) * 64, (idx >> 5) * 64, tl);
    }
}

// ---------------- prep2: w_q_b^T + w_kv_b^T ----------------------------------
__global__ __launch_bounds__(256) void prep2(
    const float* __restrict__ w_q_b, __bf16* __restrict__ wbuf,
    const float* __restrict__ w_kv_b, __bf16* __restrict__ wbuf2)
{
    __shared__ __bf16 tl[64][72];
    const int b = blockIdx.x;
    if (b < 1152) {
        tc_body(w_q_b, wbuf, 1536, 3072, (b % 24) * 64, (b / 24) * 64, tl);
    } else {
        int idx = b - 1152;
        tc_body(w_kv_b, wbuf2, 512, 4096, (idx & 7) * 64, (idx >> 3) * 64, tl);
    }
}

// ---------------- GEMM body: C[128,128] tile at (m0,n0) ----------------------
template <typename TC>
__device__ __forceinline__ void gemm_body(
    const __bf16* __restrict__ A, const __bf16* __restrict__ Bt,
    TC* __restrict__ C, int K, int Nstore, int ldc, int m0, int n0,
    __bf16* As, __bf16* Bs)
{
    const int tid = threadIdx.x, lane = tid & 63, wid = tid >> 6;
    const int l15 = lane & 15, lg = lane >> 4;
    const int wr = (wid >> 1) * 64, wc = (wid & 1) * 64;

    const int srow = wid * 32 + (lane >> 3);
    const int scol = ((lane & 7) ^ (lane >> 3)) * 8;
    const __bf16* Ag = A  + (size_t)(m0 + srow) * K + scol;
    const __bf16* Bg = Bt + (size_t)(n0 + srow) * K + scol;
    const int lbase = wid * 4096;

    f32x4 acc[4][4] = {};

    {
        char* la = (char*)As + lbase;
        char* lb = (char*)Bs + lbase;
        #pragma unroll
        for (int i = 0; i < 4; ++i) {
            gld_lds16(Ag + (size_t)i * 8 * K, la + i * 1024);
            gld_lds16(Bg + (size_t)i * 8 * K, lb + i * 1024);
        }
    }
    __syncthreads();

    int cur = 0;
    for (int k0 = 0; k0 < K; k0 += 64) {
        if (k0 + 64 < K) {
            char* la = (char*)As + (cur ^ 1) * 16384 + lbase;
            char* lb = (char*)Bs + (cur ^ 1) * 16384 + lbase;
            #pragma unroll
            for (int i = 0; i < 4; ++i) {
                gld_lds16(Ag + (size_t)i * 8 * K + k0 + 64, la + i * 1024);
                gld_lds16(Bg + (size_t)i * 8 * K + k0 + 64, lb + i * 1024);
            }
        }

        bf16x8 af[4][2], bf[4][2];
        #pragma unroll
        for (int i = 0; i < 4; ++i) {
            const int Ra = wr + i * 16 + l15;
            const int Rb = wc + i * 16 + l15;
            const int ca = (lg ^ (Ra & 7)) * 16;
            const int cb = (lg ^ (Rb & 7)) * 16;
            const char* pa = (const char*)As + cur * 16384 + Ra * 128;
            const char* pb = (const char*)Bs + cur * 16384 + Rb * 128;
            af[i][0] = *reinterpret_cast<const bf16x8*>(pa + ca);
            af[i][1] = *reinterpret_cast<const bf16x8*>(pa + (ca ^ 64));
            bf[i][0] = *reinterpret_cast<const bf16x8*>(pb + cb);
            bf[i][1] = *reinterpret_cast<const bf16x8*>(pb + (cb ^ 64));
        }
        #pragma unroll
        for (int h = 0; h < 2; ++h)
            #pragma unroll
            for (int i = 0; i < 4; ++i)
                #pragma unroll
                for (int j = 0; j < 4; ++j)
                    acc[i][j] = __builtin_amdgcn_mfma_f32_16x16x32_bf16(af[i][h], bf[j][h], acc[i][j], 0, 0, 0);

        __syncthreads();
        cur ^= 1;
    }

    #pragma unroll
    for (int i = 0; i < 4; ++i)
        #pragma unroll
        for (int j = 0; j < 4; ++j)
            #pragma unroll
            for (int e = 0; e < 4; ++e) {
                int r = m0 + wr + i * 16 + lg * 4 + e;
                int c = n0 + wc + j * 16 + l15;
                if (c < Nstore)
                    C[(size_t)r * ldc + c] = (TC)acc[i][j][e];
            }
}

template <typename TC>
__global__ __launch_bounds__(256) void gemm_bt(
    const __bf16* __restrict__ A, const __bf16* __restrict__ Bt,
    TC* __restrict__ C, int M, int N, int K, int Nstore, int ldc)
{
    __shared__ __bf16 As[2 * 128 * 64];
    __shared__ __bf16 Bs[2 * 128 * 64];
    gemm_body<TC>(A, Bt, C, K, Nstore, ldc, blockIdx.x * 128, blockIdx.y * 128, As, Bs);
}

__global__ __launch_bounds__(256) void gemm_bt_pair(
    const __bf16* __restrict__ A0, const __bf16* __restrict__ B0, __bf16* __restrict__ C0,
    int N0, int K0, int nby0,
    const __bf16* __restrict__ A1, const __bf16* __restrict__ B1, __bf16* __restrict__ C1,
    int N1, int K1)
{
    __shared__ __bf16 As[2 * 128 * 64];
    __shared__ __bf16 Bs[2 * 128 * 64];
    if ((int)blockIdx.y < nby0)
        gemm_body<__bf16>(A0, B0, C0, K0, N0, N0, blockIdx.x * 128, blockIdx.y * 128, As, Bs);
    else
        gemm_body<__bf16>(A1, B1, C1, K1, N1, N1, blockIdx.x * 128, (blockIdx.y - nby0) * 128, As, Bs);
}

// ---------------- Fused RMSNorm: q (1536) + kv (512) per row ------------------
__global__ __launch_bounds__(256) void rmsnorm_fused(
    const __bf16* __restrict__ qkv_a,
    const float* __restrict__ qw, const float* __restrict__ kw,
    __bf16* __restrict__ q_a_n, __bf16* __restrict__ kv_a_n)
{
    const int t = blockIdx.x, tid = threadIdx.x, wid = tid >> 6;
    const bool isq = tid < 192;
    const __bf16* src = qkv_a + (size_t)t * 2176 + (isq ? tid * 8 : 1536 + (tid - 192) * 8);
    float x[8];
    float ss = 0.f;
    bf16x8 v = *reinterpret_cast<const bf16x8*>(src);
    #pragma unroll
    for (int e = 0; e < 8; ++e) { x[e] = (float)v[e]; ss += x[e] * x[e]; }
    #pragma unroll
    for (int m = 1; m < 64; m <<= 1) ss += __shfl_xor(ss, m, 64);
    __shared__ float red[4];
    if ((tid & 63) == 0) red[wid] = ss;
    __syncthreads();
    float scale;
    const float* w;
    if (isq) {
        scale = rsqrtf((red[0] + red[1] + red[2]) / 1536.f + 1e-6f);
        w = qw + tid * 8;
    } else {
        scale = rsqrtf(red[3] / 512.f + 1e-6f);
        w = kw + (tid - 192) * 8;
    }
    float4 w0 = *reinterpret_cast<const float4*>(w);
    float4 w1 = *reinterpret_cast<const float4*>(w + 4);
    bf16x8 o;
    o[0] = (__bf16)(x[0] * scale * w0.x); o[1] = (__bf16)(x[1] * scale * w0.y);
    o[2] = (__bf16)(x[2] * scale * w0.z); o[3] = (__bf16)(x[3] * scale * w0.w);
    o[4] = (__bf16)(x[4] * scale * w1.x); o[5] = (__bf16)(x[5] * scale * w1.y);
    o[6] = (__bf16)(x[6] * scale * w1.z); o[7] = (__bf16)(x[7] * scale * w1.w);
    if (isq)
        *reinterpret_cast<bf16x8*>(q_a_n + (size_t)t * 1536 + tid * 8) = o;
    else
        *reinterpret_cast<bf16x8*>(kv_a_n + (size_t)t * 512 + (tid - 192) * 8) = o;
}

// ---------------- Fused RoPE(q)+Kprep  |  V-transpose (one launch) ------------
__global__ __launch_bounds__(256) void rope_vtrans(
    const int* __restrict__ positions, __bf16* __restrict__ q,
    const __bf16* __restrict__ kv, const __bf16* __restrict__ qkv_a,
    __bf16* __restrict__ kh, __bf16* __restrict__ vt)
{
    const int b = blockIdx.x, tid = threadIdx.x;
    if (b < 2048) {
        const int t = b;
        __shared__ float cs[32], sn[32];
        __shared__ __bf16 kpe[64];
        if (tid < 32) {
            float pos = (float)positions[t];
            float invf = powf(10000.f, -(float)tid / 32.f);
            float c = cosf(pos * invf), s = sinf(pos * invf);
            cs[tid] = c; sn[tid] = s;
            float x1 = (float)qkv_a[(size_t)t * 2176 + 2048 + 2 * tid];
            float x2 = (float)qkv_a[(size_t)t * 2176 + 2049 + 2 * tid];
            kpe[2 * tid]     = (__bf16)(x1 * c - x2 * s);
            kpe[2 * tid + 1] = (__bf16)(x2 * c + x1 * s);
        }
        __syncthreads();
        #pragma unroll
        for (int it = 0; it < 2; ++it) {
            int p = tid + it * 256;
            int h = p >> 5, i = p & 31;
            size_t base = (size_t)t * 3072 + h * 192 + 128 + 2 * i;
            float x1 = (float)q[base], x2 = (float)q[base + 1];
            q[base]     = (__bf16)(x1 * cs[i] - x2 * sn[i]);
            q[base + 1] = (__bf16)(x2 * cs[i] + x1 * sn[i]);
        }
        // kh assembly (chunk-swizzled: rule 21 — gld_lds stages linearly)
        const int h = tid >> 4, c = tid & 15;
        const int sw = t & 7;
        bf16x8 v = *reinterpret_cast<const bf16x8*>(kv + (size_t)t * 4096 + h * 256 + c * 8);
        *reinterpret_cast<bf16x8*>(kh + ((size_t)h * T_ + t) * 192 + (c ^ sw) * 8) = v;
        if (c < 8) {
            bf16x8 p = *reinterpret_cast<const bf16x8*>(&kpe[c * 8]);
            *reinterpret_cast<bf16x8*>(kh + ((size_t)h * T_ + t) * 192 + 128 + (c ^ sw) * 8) = p;
        }
    } else {
        __shared__ __bf16 tile[128][72];
        const int idx = b - 2048;
        const int t0 = (idx & 31) * 64;
        const int h  = idx >> 5;
        #pragma unroll
        for (int it = 0; it < 4; ++it) {
            int chunk = tid + it * 256;
            int r = chunk >> 4;
            int d8 = (chunk & 15) * 8;
            bf16x8 v = *reinterpret_cast<const bf16x8*>(kv + (size_t)(t0 + r) * 4096 + h * 256 + 128 + d8);
            #pragma unroll
            for (int e = 0; e < 8; ++e) tile[d8 + e][r] = v[e];
        }
        __syncthreads();
        #pragma unroll
        for (int it = 0; it < 4; ++it) {
            int chunk = tid + it * 256;
            int d = chunk >> 3;
            int t8 = (chunk & 7) * 8;
            bf16x8 v = *reinterpret_cast<const bf16x8*>(&tile[d][t8]);
            *reinterpret_cast<bf16x8*>(vt + ((size_t)h * 128 + d) * 2048 + t0 + t8) = v;
        }
    }
}

// ---------------- Flash attention (+ fused w_o transpose tail) ----------------
// blocks [0,1024): 4-wave q-tile attention, KV-split 4, K async-staged via
// global_load_lds. V loads issued BEFORE the next stage so PV's implicit
// vmcnt wait leaves the stage in flight (FIFO: [vf x8, stage x12] -> vmcnt(12)).
// blocks [1024,2048): w_o transpose tiles (fill attention's drain tail).
__device__ inline unsigned pk2(float a, float b) {
    union { __bf16 h[2]; unsigned u; } z;
    z.h[0] = (__bf16)a; z.h[1] = (__bf16)b;
    return z.u;
}

union AttnSmem {
    char kstage[4][12288];           // 4 waves x 12KB K tile (49,152 B)
    struct {
        float mls[2][4][32];
        float linv[32];
        float obuf[32][129];
    } c;
    __bf16 tl[64][72];               // w_o transpose tile
};

__global__ __launch_bounds__(256, 2) void attn_wo(
    const __bf16* __restrict__ q, const __bf16* __restrict__ kh,
    const __bf16* __restrict__ vt, __bf16* __restrict__ attn,
    const float* __restrict__ w_o, __bf16* __restrict__ wot)
{
    __shared__ AttnSmem sm;
    const int b = blockIdx.x;
    if (b >= 1024) {   // w_o transpose tile: 2048x2048, 32x32 tiles
        const int idx = b - 1024;
        tc_body(w_o, wot, 2048, 2048, (idx & 31) * 64, (idx >> 5) * 64, sm.tl);
        return;
    }

    const int tid = threadIdx.x;
    const int lane = tid & 63, wid = tid >> 6;      // 0..3
    const int q31 = lane & 31, hi = lane >> 5;
    const int h = b & 15;
    const int qt = 63 - (b >> 4);                    // heavy-first
    const int q0 = qt * 32;
    const int ntile = qt + 1;

    const __bf16* Khh = kh + (size_t)h * T_ * 192;
    const __bf16* Vt  = vt + (size_t)h * 128 * T_;
    const __bf16* Qp  = q + (size_t)(q0 + q31) * 3072 + h * 192;

    bf16x8 aq[12];
    #pragma unroll
    for (int c = 0; c < 12; ++c)
        aq[c] = *reinterpret_cast<const bf16x8*>(Qp + c * 16 + hi * 8);

    f32x16 o[4] = {};
    float m_i = -1e30f, l_i = 0.f;

    char* kbuf = sm.kstage[wid];

    // prologue: stage tile `wid`
    if (wid < ntile) {
        const __bf16* src = Khh + (size_t)(wid * 32) * 192 + lane * 8;
        #pragma unroll
        for (int i = 0; i < 12; ++i)
            gld_lds16(src + i * 512, kbuf + i * 1024);
    }

    for (int it = wid; it < ntile; it += 4) {
        // staging of this tile complete
        asm volatile("s_waitcnt vmcnt(0)" ::: "memory");
        __builtin_amdgcn_sched_barrier(0);

        // K fragments from LDS (swizzled chunks)
        bf16x8 kc[12];
        #pragma unroll
        for (int c = 0; c < 12; ++c) {
            const int p = (2 * c + hi) ^ (q31 & 7);
            kc[c] = *reinterpret_cast<const bf16x8*>(kbuf + q31 * 384 + p * 16);
        }
        asm volatile("s_waitcnt lgkmcnt(0)" ::: "memory");
        __builtin_amdgcn_sched_barrier(0);

        const int s0 = it * 32;
        // V fragments FIRST: PV's wait can then be vmcnt(12), stage stays in flight
        bf16x8 vf[4][2];
        #pragma unroll
        for (int n = 0; n < 4; ++n)
            #pragma unroll
            for (int m = 0; m < 2; ++m)
                vf[n][m] = *reinterpret_cast<const bf16x8*>(
                    Vt + (size_t)(n * 32 + q31) * 2048 + s0 + (2 * m + hi) * 8);

        // issue next stage (async, un-sinkable; in flight through next loop top)
        const bool notlast = (it + 4 < ntile);
        if (notlast) {
            const __bf16* src = Khh + (size_t)((it + 4) * 32) * 192 + lane * 8;
            #pragma unroll
            for (int i = 0; i < 12; ++i)
                gld_lds16(src + i * 512, kbuf + i * 1024);
        }

        // QK^T (swapped): S^T[kpos][q]
        f32x16 sA = {}, sB = {};
        __builtin_amdgcn_s_setprio(1);
        #pragma unroll
        for (int c = 0; c < 12; c += 2) {
            sA = __builtin_amdgcn_mfma_f32_32x32x16_bf16(kc[c],     aq[c],     sA, 0, 0, 0);
            sB = __builtin_amdgcn_mfma_f32_32x32x16_bf16(kc[c + 1], aq[c + 1], sB, 0, 0, 0);
        }
        __builtin_amdgcn_s_setprio(0);

        float v[16];
        #pragma unroll
        for (int r = 0; r < 16; ++r) v[r] = (sA[r] + sB[r]) * SCALE_;
        if (it == qt) {   // diagonal tile: mask k > q
            #pragma unroll
            for (int r = 0; r < 16; ++r) {
                int crow = (r & 3) + 8 * (r >> 2) + 4 * hi;
                if (crow > q31) v[r] = -1e30f;
            }
        }
        float mx = v[0];
        #pragma unroll
        for (int r = 1; r < 16; ++r) mx = fmaxf(mx, v[r]);
        mx = fmaxf(mx, __shfl_xor(mx, 32, 64));
        const bool skip = __all(mx <= m_i);
        float mnew = fmaxf(m_i, mx);
        float fsc = skip ? 1.f : __expf(m_i - mnew);
        m_i = mnew;
        float ps = 0.f;
        #pragma unroll
        for (int r = 0; r < 16; ++r) { v[r] = __expf(v[r] - mnew); ps += v[r]; }
        ps += __shfl_xor(ps, 32, 64);
        l_i = l_i * fsc + ps;
        if (!skip) {
            #pragma unroll
            for (int n = 0; n < 4; ++n) o[n] *= fsc;
        }

        // pack P to bf16; exchange halves across lane^32
        unsigned w[8], xw[8];
        #pragma unroll
        for (int i = 0; i < 8; ++i) w[i] = pk2(v[2 * i], v[2 * i + 1]);
        #pragma unroll
        for (int i = 0; i < 8; ++i) xw[i] = __shfl_xor(w[i], 32, 64);
        union { unsigned u[4]; bf16x8 v; } P0, P1;
        P0.u[0] = hi ? xw[2] : w[0]; P0.u[1] = hi ? xw[3] : w[1];
        P0.u[2] = hi ? w[2] : xw[0]; P0.u[3] = hi ? w[3] : xw[1];
        P1.u[0] = hi ? xw[6] : w[4]; P1.u[1] = hi ? xw[7] : w[5];
        P1.u[2] = hi ? w[6] : xw[4]; P1.u[3] = hi ? w[7] : xw[5];

        __builtin_amdgcn_s_setprio(1);
        #pragma unroll
        for (int n = 0; n < 4; ++n) {
            o[n] = __builtin_amdgcn_mfma_f32_32x32x16_bf16(vf[n][0], P0.v, o[n], 0, 0, 0);
            o[n] = __builtin_amdgcn_mfma_f32_32x32x16_bf16(vf[n][1], P1.v, o[n], 0, 0, 0);
        }
        __builtin_amdgcn_s_setprio(0);
    }

    // all my gld_lds consumed (loop-top vmcnt); barrier, then union -> combine
    __syncthreads();
    if (hi == 0) { sm.c.mls[0][wid][q31] = m_i; sm.c.mls[1][wid][q31] = l_i; }
    __syncthreads();
    float M = fmaxf(fmaxf(sm.c.mls[0][0][q31], sm.c.mls[0][1][q31]),
                    fmaxf(sm.c.mls[0][2][q31], sm.c.mls[0][3][q31]));
    float L = sm.c.mls[1][0][q31] * __expf(sm.c.mls[0][0][q31] - M)
            + sm.c.mls[1][1][q31] * __expf(sm.c.mls[0][1][q31] - M)
            + sm.c.mls[1][2][q31] * __expf(sm.c.mls[0][2][q31] - M)
            + sm.c.mls[1][3][q31] * __expf(sm.c.mls[0][3][q31] - M);
    float F = __expf(m_i - M);
    if (wid == 0 && hi == 0) sm.c.linv[q31] = 1.f / L;

    #pragma unroll
    for (int rd = 0; rd < 4; ++rd) {
        if (wid == rd) {
            if (rd == 0) {
                #pragma unroll
                for (int n = 0; n < 4; ++n)
                    #pragma unroll
                    for (int r = 0; r < 16; ++r) {
                        int d = (r & 3) + 8 * (r >> 2) + 4 * hi + 32 * n;
                        sm.c.obuf[q31][d] = F * o[n][r];
                    }
            } else {
                #pragma unroll
                for (int n = 0; n < 4; ++n)
                    #pragma unroll
                    for (int r = 0; r < 16; ++r) {
                        int d = (r & 3) + 8 * (r >> 2) + 4 * hi + 32 * n;
                        sm.c.obuf[q31][d] += F * o[n][r];
                    }
            }
        }
        __syncthreads();
    }

    // store: 256 threads x 2 iters = 32 rows x 16 chunks
    #pragma unroll
    for (int it2 = 0; it2 < 2; ++it2) {
        int cidx = tid + it2 * 256;
        int row = cidx >> 4, c8 = (cidx & 15) * 8;
        float inv = sm.c.linv[row];
        bf16x8 vv;
        #pragma unroll
        for (int j = 0; j < 8; ++j)
            vv[j] = (__bf16)(sm.c.obuf[row][c8 + j] * inv);
        *reinterpret_cast<bf16x8*>(attn + (size_t)(q0 + row) * 2048 + h * 128 + c8) = vv;
    }
}

// -----------------------------------------------------------------------------
extern "C" void kernel_launch(void* const* d_in, const int* in_sizes, int n_in,
                              void* d_out, int out_size, void* d_ws, size_t ws_size,
                              hipStream_t stream)
{
    const int*   positions = (const int*)d_in[0];
    const float* hidden    = (const float*)d_in[1];
    const float* w_q_a     = (const float*)d_in[2];
    const float* q_a_ln_w  = (const float*)d_in[3];
    const float* w_q_b     = (const float*)d_in[4];
    const float* w_kv_a    = (const float*)d_in[5];
    const float* kv_a_ln_w = (const float*)d_in[6];
    const float* w_kv_b    = (const float*)d_in[7];
    const float* w_o       = (const float*)d_in[8];

    char* ws = (char*)d_ws;
    __bf16* hidden_bf = (__bf16*)(ws);                 // 2048x2048      8,388,608
    __bf16* vt        = (__bf16*)(ws);                 // 16x128x2048 (overlays hidden_bf)
    __bf16* wbuf      = (__bf16*)(ws + 8388608);       // W^T scratch    9,437,184
    __bf16* qkv_a     = (__bf16*)(ws + 17825792);      // 2048x2176      8,912,896
    __bf16* attn      = (__bf16*)(ws + 17825792);      // 2048x2048 (overlays qkv_a)
    __bf16* q_a_n     = (__bf16*)(ws + 26738688);      // 2048x1536      6,291,456
    __bf16* q         = (__bf16*)(ws + 33030144);      // 2048x3072     12,582,912
    __bf16* kv_a_n    = (__bf16*)(ws + 45613056);      // 2048x512       2,097,152
    __bf16* kv        = (__bf16*)(ws + 47710208);      // 2048x4096     16,777,216
    __bf16* wot       = (__bf16*)(ws + 47710208);      // 2048x2048 w_o^T (overlays kv after use)
    __bf16* kh        = (__bf16*)(ws + 64487424);      // 16x2048x192   12,582,912
    __bf16* wbuf2     = (__bf16*)(ws + 77070336);      // 512x4096 W^T   4,194,304

    dim3 blk(256);
    prep1<<<dim3(3136), blk, 0, stream>>>(hidden, hidden_bf, w_q_a, w_kv_a, wbuf);
    gemm_bt<__bf16><<<dim3(16, 17), blk, 0, stream>>>(hidden_bf, wbuf, qkv_a, 2048, 2176, 2048, 2112, 2176);
    rmsnorm_fused<<<dim3(2048), blk, 0, stream>>>(qkv_a, q_a_ln_w, kv_a_ln_w, q_a_n, kv_a_n);

    prep2<<<dim3(1664), blk, 0, stream>>>(w_q_b, wbuf, w_kv_b, wbuf2);
    gemm_bt_pair<<<dim3(16, 56), blk, 0, stream>>>(
        q_a_n, wbuf, q, 3072, 1536, 24,
        kv_a_n, wbuf2, kv, 4096, 512);

    rope_vtrans<<<dim3(2560), blk, 0, stream>>>(positions, q, kv, qkv_a, kh, vt);
    attn_wo<<<dim3(2048), blk, 0, stream>>>(q, kh, vt, attn, w_o, wot);

    gemm_bt<float><<<dim3(16, 16), blk, 0, stream>>>(attn, wot, (float*)d_out, 2048, 2048, 2048, 2048, 2048);
}